// Round 2
// baseline (279.610 us; speedup 1.0000x reference)
//
#include <hip/hip_runtime.h>

#define NROWS 131072          // 64*2048
#define D 64
#define K 512
#define TPB 512
#define NBLOCKS (NROWS/TPB)   // 256

#define LOSS_OFF (NROWS*D)    // 8388608
#define PERP_OFF (LOSS_OFF+1)
#define IDX_OFF  (LOSS_OFF+2)

// ws layout: [0]: float wsum; [256B]: int hist[512]; [4096B]: float e2[512]

__global__ __launch_bounds__(64) void vq_norms(
    const float* __restrict__ emb, float* __restrict__ e2)
{
    int k = blockIdx.x * 64 + threadIdx.x;   // grid 8 x 64
    const float* e = emb + (size_t)k * D;
    float s0=0.f,s1=0.f,s2=0.f,s3=0.f;
    #pragma unroll
    for (int d = 0; d < D; d += 4) {
        s0 = fmaf(e[d+0], e[d+0], s0);
        s1 = fmaf(e[d+1], e[d+1], s1);
        s2 = fmaf(e[d+2], e[d+2], s2);
        s3 = fmaf(e[d+3], e[d+3], s3);
    }
    e2[k] = (s0+s1)+(s2+s3);   // same order as round-1 (absmax 0.0 preserved)
}

__global__ __launch_bounds__(TPB) void vq_main(
    const float* __restrict__ x, const float* __restrict__ emb,
    const float* __restrict__ e2n,
    float* __restrict__ out, float* __restrict__ wsum, int* __restrict__ whist)
{
    __shared__ int shist[K];
    for (int i = threadIdx.x; i < K; i += TPB) shist[i] = 0;
    __syncthreads();

    const int r = blockIdx.x * TPB + threadIdx.x;

    // row into registers (each lane owns one 256B row; L1 makes this fully used)
    float xr[D];
    {
        const float4* p = reinterpret_cast<const float4*>(x + (size_t)r * D);
        #pragma unroll
        for (int i = 0; i < D/4; ++i) {
            float4 v = p[i];
            xr[4*i+0]=v.x; xr[4*i+1]=v.y; xr[4*i+2]=v.z; xr[4*i+3]=v.w;
        }
    }

    float best = 3.4e38f;
    int   bi = 0;

    // k loop: codebook addresses are wave-uniform -> scalar/L1 path, no LDS.
    #pragma unroll 2
    for (int k = 0; k < K; ++k) {
        const float* e = emb + k * D;        // uniform address
        float a0=0.f,a1=0.f,a2=0.f,a3=0.f;
        #pragma unroll
        for (int d = 0; d < D; d += 4) {
            a0 = fmaf(xr[d+0], e[d+0], a0);
            a1 = fmaf(xr[d+1], e[d+1], a1);
            a2 = fmaf(xr[d+2], e[d+2], a2);
            a3 = fmaf(xr[d+3], e[d+3], a3);
        }
        float dist = fmaf(-2.f, (a0+a1)+(a2+a3), e2n[k]);
        if (dist < best) { best = dist; bi = k; }   // strict <: first-min like argmin
    }

    // epilogue: gather code from global (L1/L2-hot), straight-through out,
    // squared-diff accumulation, index, histogram
    float dsum = 0.f;
    {
        const float4* eq = reinterpret_cast<const float4*>(emb + (size_t)bi * D);
        float4* o = reinterpret_cast<float4*>(out + (size_t)r * D);
        #pragma unroll
        for (int i = 0; i < D/4; ++i) {
            float4 q = eq[i];
            float4 v;
            float d0,d1,d2,d3;
            d0 = q.x - xr[4*i+0]; v.x = xr[4*i+0] + d0; dsum = fmaf(d0,d0,dsum);
            d1 = q.y - xr[4*i+1]; v.y = xr[4*i+1] + d1; dsum = fmaf(d1,d1,dsum);
            d2 = q.z - xr[4*i+2]; v.z = xr[4*i+2] + d2; dsum = fmaf(d2,d2,dsum);
            d3 = q.w - xr[4*i+3]; v.w = xr[4*i+3] + d3; dsum = fmaf(d3,d3,dsum);
            o[i] = v;
        }
    }

    out[IDX_OFF + r] = (float)bi;
    atomicAdd(&shist[bi], 1);

    // wave reduction of squared-diff, one global atomic per wave
    #pragma unroll
    for (int off = 32; off > 0; off >>= 1)
        dsum += __shfl_xor(dsum, off, 64);
    if ((threadIdx.x & 63) == 0)
        atomicAdd(wsum, dsum);

    __syncthreads();
    for (int i = threadIdx.x; i < K; i += TPB)
        if (shist[i]) atomicAdd(&whist[i], shist[i]);
}

__global__ __launch_bounds__(K) void vq_finalize(
    const float* __restrict__ wsum, const int* __restrict__ whist,
    float* __restrict__ out)
{
    __shared__ float red[K];
    int t = threadIdx.x;
    float c = (float)whist[t];
    float p = c / (float)NROWS;
    red[t] = p * logf(p + 1e-10f);
    __syncthreads();
    for (int s = K/2; s > 0; s >>= 1) {
        if (t < s) red[t] += red[t+s];
        __syncthreads();
    }
    if (t == 0) {
        out[PERP_OFF] = expf(-red[0]);
        out[LOSS_OFF] = 0.25f * (wsum[0] / (float)(NROWS*D));
    }
}

extern "C" void kernel_launch(void* const* d_in, const int* in_sizes, int n_in,
                              void* d_out, int out_size, void* d_ws, size_t ws_size,
                              hipStream_t stream)
{
    const float* x   = (const float*)d_in[0];
    const float* emb = (const float*)d_in[1];
    float* out   = (float*)d_out;
    float* wsum  = (float*)d_ws;                          // 1 float @ 0
    int*   whist = (int*)((char*)d_ws + 256);             // 512 ints @ 256B
    float* e2    = (float*)((char*)d_ws + 4096);          // 512 floats @ 4096B

    hipMemsetAsync(d_ws, 0, 4096, stream);                // zero wsum + hist
    vq_norms<<<K/64, 64, 0, stream>>>(emb, e2);
    vq_main<<<NBLOCKS, TPB, 0, stream>>>(x, emb, e2, out, wsum, whist);
    vq_finalize<<<1, K, 0, stream>>>(wsum, whist, out);
}